// Round 2
// baseline (36.175 us; speedup 1.0000x reference)
//
#include <hip/hip_runtime.h>

#define D 64
#define STR 72  // LDS row stride (bf16 elems): >64, multiple of 8, avoids 128B-stride conflicts

typedef __attribute__((ext_vector_type(8))) short bf16x8;
typedef __attribute__((ext_vector_type(4))) float f32x4;

static __device__ __forceinline__ unsigned short f2bf(float f) {
  unsigned u = __builtin_bit_cast(unsigned, f);
  u += 0x7fffu + ((u >> 16) & 1u);  // RNE
  return (unsigned short)(u >> 16);
}

__global__ __launch_bounds__(64)
void seq_attn_kernel(const float* __restrict__ h,
                     const int* __restrict__ sse,  // int32! jnp.asarray(int64)->int32 (x64 disabled)
                     float* __restrict__ out) {
  __shared__ unsigned short Hs[64 * STR];   // H rows (bf16); reused later for P
  __shared__ unsigned short HTs[64 * STR];  // H^T (feature-major), zero-padded keys

  const int s = blockIdx.x;
  const int lane = threadIdx.x;
  const int start = sse[2 * s];
  const int L = sse[2 * s + 1] - start;
  const int nt = (L + 15) >> 4;  // live 16-row tiles
  const int g = lane >> 4;       // 0..3
  const int c16 = lane & 15;     // 0..15

  // zero HT so pad keys (m >= L) contribute exactly 0 in PV (no NaN garbage)
  #pragma unroll
  for (int i = 0; i < 9; ++i)
    *(float4*)&HTs[(i * 64 + lane) * 8] = make_float4(0.f, 0.f, 0.f, 0.f);
  __syncthreads();

  // stage fp32 global -> bf16 LDS (row-major + transposed). float4: 1KB/instr coalesced.
  {
    const float* src = h + (size_t)start * D;
    const int rr = lane >> 4;
    const int c4 = (lane & 15) * 4;
    const int iters = L >> 2;  // L % 8 == 0 always
    for (int it = 0; it < iters; ++it) {
      const int r = it * 4 + rr;
      const float4 v = *(const float4*)(src + r * D + c4);
      const unsigned short b0 = f2bf(v.x), b1 = f2bf(v.y), b2 = f2bf(v.z), b3 = f2bf(v.w);
      *(ushort4*)&Hs[r * STR + c4] = make_ushort4(b0, b1, b2, b3);
      HTs[(c4 + 0) * STR + r] = b0;
      HTs[(c4 + 1) * STR + r] = b1;
      HTs[(c4 + 2) * STR + r] = b2;
      HTs[(c4 + 3) * STR + r] = b3;
    }
  }
  __syncthreads();

  // QK^T fragments: by symmetry of S = H H^T, A-frag of row-tile t == B-frag of col-tile t.
  bf16x8 hf[4][2];
  #pragma unroll
  for (int t = 0; t < 4; ++t)
    #pragma unroll
    for (int kb = 0; kb < 2; ++kb)
      hf[t][kb] = *(const bf16x8*)&Hs[(t * 16 + c16) * STR + kb * 32 + g * 8];

  f32x4 acc[4][4];
  #pragma unroll
  for (int ti = 0; ti < 4; ++ti)
    #pragma unroll
    for (int tj = 0; tj < 4; ++tj) {
      f32x4 z = {0.f, 0.f, 0.f, 0.f};
      acc[ti][tj] = z;
    }

  #pragma unroll
  for (int ti = 0; ti < 4; ++ti) {
    if (ti >= nt) continue;  // skip dead query tiles
    #pragma unroll
    for (int tj = 0; tj < 4; ++tj)
      #pragma unroll
      for (int kb = 0; kb < 2; ++kb)
        acc[ti][tj] = __builtin_amdgcn_mfma_f32_16x16x32_bf16(
            hf[ti][kb], hf[tj][kb], acc[ti][tj], 0, 0, 0);
  }

  // softmax over key index m. C layout: row = 16*ti + 4*g + r, col m = 16*tj + c16.
  float inv[4][4];
  #pragma unroll
  for (int ti = 0; ti < 4; ++ti) {
    if (ti >= nt) continue;
    #pragma unroll
    for (int r = 0; r < 4; ++r) {
      float mx = -1e30f;
      #pragma unroll
      for (int tj = 0; tj < 4; ++tj) {
        const float sv = (tj * 16 + c16 < L) ? acc[ti][tj][r] : -1e30f;  // index-mask kills NaN pads
        acc[ti][tj][r] = sv;
        mx = fmaxf(mx, sv);
      }
      #pragma unroll
      for (int off = 1; off < 16; off <<= 1)
        mx = fmaxf(mx, __shfl_xor(mx, off, 64));
      float sum = 0.f;
      #pragma unroll
      for (int tj = 0; tj < 4; ++tj) {
        const float p = __expf(acc[ti][tj][r] - mx);  // masked: exp(-1e30 - mx) -> 0
        acc[ti][tj][r] = p;
        sum += p;
      }
      #pragma unroll
      for (int off = 1; off < 16; off <<= 1)
        sum += __shfl_xor(sum, off, 64);
      inv[ti][r] = 1.0f / sum;  // defer normalization to epilogue
    }
  }

  __syncthreads();  // hf fragment reads of Hs are done; reuse Hs for P
  #pragma unroll
  for (int ti = 0; ti < 4; ++ti) {
    if (ti >= nt) continue;
    #pragma unroll
    for (int tj = 0; tj < 4; ++tj)
      #pragma unroll
      for (int r = 0; r < 4; ++r)
        Hs[(ti * 16 + g * 4 + r) * STR + tj * 16 + c16] = f2bf(acc[ti][tj][r]);
  }
  __syncthreads();

  // PV: A = P (rows of Hs-as-P), B = H (read via HTs rows -> contiguous 16B frag loads)
  bf16x8 pf[4][2], vf[4][2];
  #pragma unroll
  for (int t = 0; t < 4; ++t)
    #pragma unroll
    for (int kb = 0; kb < 2; ++kb) {
      pf[t][kb] = *(const bf16x8*)&Hs[(t * 16 + c16) * STR + kb * 32 + g * 8];
      vf[t][kb] = *(const bf16x8*)&HTs[(t * 16 + c16) * STR + kb * 32 + g * 8];
    }

  f32x4 o[4][4];
  #pragma unroll
  for (int ti = 0; ti < 4; ++ti)
    #pragma unroll
    for (int tj = 0; tj < 4; ++tj) {
      f32x4 z = {0.f, 0.f, 0.f, 0.f};
      o[ti][tj] = z;
    }

  #pragma unroll
  for (int ti = 0; ti < 4; ++ti) {
    if (ti >= nt) continue;
    #pragma unroll
    for (int tjd = 0; tjd < 4; ++tjd)
      #pragma unroll
      for (int kb = 0; kb < 2; ++kb)
        o[ti][tjd] = __builtin_amdgcn_mfma_f32_16x16x32_bf16(
            pf[ti][kb], vf[tjd][kb], o[ti][tjd], 0, 0, 0);
  }

  // scale rows by 1/sum and store (row mapping identical to softmax regs)
  #pragma unroll
  for (int ti = 0; ti < 4; ++ti) {
    if (ti >= nt) continue;
    #pragma unroll
    for (int r = 0; r < 4; ++r) {
      const int row = ti * 16 + g * 4 + r;
      if (row < L) {
        float* dst = out + (size_t)(start + row) * D;
        const float sc = inv[ti][r];
        #pragma unroll
        for (int tjd = 0; tjd < 4; ++tjd)
          dst[tjd * 16 + c16] = o[ti][tjd][r] * sc;
      }
    }
  }
}

extern "C" void kernel_launch(void* const* d_in, const int* in_sizes, int n_in,
                              void* d_out, int out_size, void* d_ws, size_t ws_size,
                              hipStream_t stream) {
  const float* h = (const float*)d_in[0];
  const int* sse = (const int*)d_in[1];  // int32 on device (JAX x64 disabled)
  float* out = (float*)d_out;
  const int nseq = in_sizes[1] / 2;  // 4096
  seq_attn_kernel<<<nseq, 64, 0, stream>>>(h, sse, out);
}

// Round 3
// 27.768 us; speedup vs baseline: 1.3028x; 1.3028x over previous
//
#include <hip/hip_runtime.h>

#define D 64
#define STR 72  // LDS row stride in bf16 elems: 16B-aligned rows, non-pow2 dword stride

typedef __attribute__((ext_vector_type(8))) short bf16x8;
typedef __attribute__((ext_vector_type(4))) float f32x4;
typedef __attribute__((ext_vector_type(4))) unsigned int u32x4;

static __device__ __forceinline__ unsigned short f2bf(float f) {
  unsigned u = __builtin_bit_cast(unsigned, f);
  u += 0x7fffu + ((u >> 16) & 1u);  // RNE
  return (unsigned short)(u >> 16);
}

// One wave per sequence. Single 9.2KB LDS buffer -> ~16 blocks/CU (was 8 at 18.4KB).
__global__ __launch_bounds__(64, 4)
void seq_attn_kernel(const float* __restrict__ h,
                     const int* __restrict__ sse,  // int32 (JAX x64 disabled)
                     float* __restrict__ out) {
  __shared__ unsigned short Hs[64 * STR];  // H rows (bf16), zero-padded; later reused for P

  const int s = blockIdx.x;
  const int lane = threadIdx.x;
  const int start = sse[2 * s];
  const int L = sse[2 * s + 1] - start;
  const int nt = (L + 15) >> 4;  // live 16-row tiles
  const int g = lane >> 4;       // 0..3
  const int c16 = lane & 15;     // 0..15

  // ---- stage H fp32->bf16: all loads issued up front (one latency, not L/4) ----
  {
    const float* src = h + (size_t)start * D;
    const int c4 = c16 * 4;
    float4 va[8], vb[8];
    #pragma unroll
    for (int it = 0; it < 8; ++it) {
      const int r = it * 4 + g;
      const int rc = (r < L) ? r : 0;  // clamp: safe, masked at write
      va[it] = *(const float4*)(src + rc * D + c4);
    }
    const bool hi = (L > 32);  // block-uniform branch skips dead upper-half loads
    #pragma unroll
    for (int it = 0; it < 8; ++it) {
      const int r = 32 + it * 4 + g;
      const int rc = (r < L) ? r : 0;
      vb[it] = hi ? *(const float4*)(src + rc * D + c4) : make_float4(0.f, 0.f, 0.f, 0.f);
    }
    #pragma unroll
    for (int it = 0; it < 8; ++it) {
      const int r = it * 4 + g;
      const bool ok = (r < L);
      ushort4 w;
      w.x = ok ? f2bf(va[it].x) : (unsigned short)0;
      w.y = ok ? f2bf(va[it].y) : (unsigned short)0;
      w.z = ok ? f2bf(va[it].z) : (unsigned short)0;
      w.w = ok ? f2bf(va[it].w) : (unsigned short)0;
      *(ushort4*)&Hs[r * STR + c4] = w;  // rows >= L get zeros (pad keys contribute 0)
    }
    #pragma unroll
    for (int it = 0; it < 8; ++it) {
      const int r = 32 + it * 4 + g;
      const bool ok = (r < L);
      ushort4 w;
      w.x = ok ? f2bf(vb[it].x) : (unsigned short)0;
      w.y = ok ? f2bf(vb[it].y) : (unsigned short)0;
      w.z = ok ? f2bf(vb[it].z) : (unsigned short)0;
      w.w = ok ? f2bf(vb[it].w) : (unsigned short)0;
      *(ushort4*)&Hs[r * STR + c4] = w;
    }
  }
  __syncthreads();  // 1-wave block: compiles to waitcnt only

  // ---- hf: A-layout fragments of H (serve as BOTH operands of S = H H^T) ----
  bf16x8 hf[4][2];
  #pragma unroll
  for (int t = 0; t < 4; ++t)
    #pragma unroll
    for (int kb = 0; kb < 2; ++kb)
      hf[t][kb] = *(const bf16x8*)&Hs[(t * 16 + c16) * STR + kb * 32 + g * 8];

  // ---- vf: B-layout fragments of H for PV, preloaded to regs BEFORE P overwrites Hs.
  // lane needs H[k=kb*32+g*8+j][t*16+c16]: column reads; compiler pairs ds_read_u16/_d16_hi.
  bf16x8 vf[4][2];
  #pragma unroll
  for (int t = 0; t < 4; ++t)
    #pragma unroll
    for (int kb = 0; kb < 2; ++kb) {
      u32x4 w;
      #pragma unroll
      for (int dd = 0; dd < 4; ++dd) {
        const int k0 = kb * 32 + g * 8 + 2 * dd;
        const unsigned lo = Hs[k0 * STR + t * 16 + c16];
        const unsigned hi2 = Hs[(k0 + 1) * STR + t * 16 + c16];
        w[dd] = lo | (hi2 << 16);
      }
      vf[t][kb] = __builtin_bit_cast(bf16x8, w);
    }

  // ---- per 16-row tile: QK^T -> softmax -> P restage -> PV -> store ----
  #pragma unroll
  for (int ti = 0; ti < 4; ++ti) {
    if (ti >= nt) continue;  // block-uniform

    f32x4 acc[4];
    #pragma unroll
    for (int tj = 0; tj < 4; ++tj) {
      f32x4 z = {0.f, 0.f, 0.f, 0.f};
      acc[tj] = z;
    }
    #pragma unroll
    for (int tj = 0; tj < 4; ++tj)
      #pragma unroll
      for (int kb = 0; kb < 2; ++kb)
        acc[tj] = __builtin_amdgcn_mfma_f32_16x16x32_bf16(
            hf[ti][kb], hf[tj][kb], acc[tj], 0, 0, 0);

    // softmax over key index. C layout: row = 16*ti + 4*g + r, col = 16*tj + c16.
    float inv[4];
    #pragma unroll
    for (int r = 0; r < 4; ++r) {
      float mx = -1e30f;
      #pragma unroll
      for (int tj = 0; tj < 4; ++tj) {
        const float sv = (tj * 16 + c16 < L) ? acc[tj][r] : -1e30f;
        acc[tj][r] = sv;
        mx = fmaxf(mx, sv);
      }
      #pragma unroll
      for (int off = 1; off < 16; off <<= 1)
        mx = fmaxf(mx, __shfl_xor(mx, off, 64));
      float sum = 0.f;
      #pragma unroll
      for (int tj = 0; tj < 4; ++tj) {
        const float p = __expf(acc[tj][r] - mx);
        acc[tj][r] = p;
        sum += p;
      }
      #pragma unroll
      for (int off = 1; off < 16; off <<= 1)
        sum += __shfl_xor(sum, off, 64);
      inv[r] = 1.0f / sum;  // normalization deferred to epilogue
    }

    // P tile (bf16) into Hs rows [16*ti, 16*ti+16) — hf/vf already in registers
    #pragma unroll
    for (int tj = 0; tj < 4; ++tj)
      #pragma unroll
      for (int r = 0; r < 4; ++r)
        Hs[(ti * 16 + g * 4 + r) * STR + tj * 16 + c16] = f2bf(acc[tj][r]);

    __syncthreads();  // orders ds_write(P) -> ds_read(pf); waitcnt only (1 wave)

    bf16x8 pf[2];
    #pragma unroll
    for (int kb = 0; kb < 2; ++kb)
      pf[kb] = *(const bf16x8*)&Hs[(ti * 16 + c16) * STR + kb * 32 + g * 8];

    f32x4 o[4];
    #pragma unroll
    for (int tjd = 0; tjd < 4; ++tjd) {
      f32x4 z = {0.f, 0.f, 0.f, 0.f};
      o[tjd] = z;
    }
    #pragma unroll
    for (int tjd = 0; tjd < 4; ++tjd)
      #pragma unroll
      for (int kb = 0; kb < 2; ++kb)
        o[tjd] = __builtin_amdgcn_mfma_f32_16x16x32_bf16(
            pf[kb], vf[tjd][kb], o[tjd], 0, 0, 0);

    #pragma unroll
    for (int r = 0; r < 4; ++r) {
      const int row = ti * 16 + g * 4 + r;
      if (row < L) {
        float* dst = out + (size_t)(start + row) * D;
        const float sc = inv[r];
        #pragma unroll
        for (int tjd = 0; tjd < 4; ++tjd)
          dst[tjd * 16 + c16] = o[tjd][r] * sc;
      }
    }
  }
}

extern "C" void kernel_launch(void* const* d_in, const int* in_sizes, int n_in,
                              void* d_out, int out_size, void* d_ws, size_t ws_size,
                              hipStream_t stream) {
  const float* h = (const float*)d_in[0];
  const int* sse = (const int*)d_in[1];
  float* out = (float*)d_out;
  const int nseq = in_sizes[1] / 2;  // 4096
  seq_attn_kernel<<<nseq, 64, 0, stream>>>(h, sse, out);
}